// Round 8
// baseline (180.763 us; speedup 1.0000x reference)
//
#include <hip/hip_runtime.h>
#include <cstdint>

#define N_IMG 1024
#define D_DIM 512
#define C_CLS 100000
#define C_PAD 100096            // 782 * 128
#define NT_N2 782               // N-tiles of 128
#define NWG (4 * NT_N2)         // 3128 blocks = 8 * 391
#define SCALE_LN2 92.33248261689366f  // 64 / ln(2)
#define COS_M 0.8775825618903728f
#define SIN_M 0.479425538604203f

typedef __attribute__((ext_vector_type(4))) int int4v;

#define GLD16(g, l) __builtin_amdgcn_global_load_lds( \
    (const __attribute__((address_space(1))) void*)(g), \
    (__attribute__((address_space(3))) void*)(l), 16, 0, 0)

static __device__ __forceinline__ uint pk4(float a, float b, float c, float d,
                                           float qs) {
  int ia = (int)rintf(a * qs), ib = (int)rintf(b * qs);
  int ic = (int)rintf(c * qs), id = (int)rintf(d * qs);
  return (ia & 255) | ((ib & 255) << 8) | ((ic & 255) << 16) | ((id & 255) << 24);
}

static __device__ __forceinline__ int dp8(uint a, uint b) {
  int s = 0;
  #pragma unroll
  for (int i = 0; i < 4; ++i)
    s += (int)(signed char)((a >> (8 * i)) & 255) *
         (int)(signed char)((b >> (8 * i)) & 255);
  return s;
}

// --------------------------- row L2-normalize + symmetric int8 quantization
__global__ __launch_bounds__(256) void norm_q(
    const float* __restrict__ src, signed char* __restrict__ dst,
    float* __restrict__ scale, float* __restrict__ inv, int nvalid, int nrows)
{
  int row = blockIdx.x * 4 + (threadIdx.x >> 6);
  int lane = threadIdx.x & 63;
  if (row >= nrows) return;
  if (row >= nvalid) {                 // pad rows: zero q + zero scale
    uint2 z; z.x = 0u; z.y = 0u;
    ((uint2*)(dst + (size_t)row * D_DIM))[lane] = z;
    if (lane == 0) scale[row] = 0.f;
    return;
  }
  const float4* sp = (const float4*)(src + (size_t)row * D_DIM);
  float4 a = sp[2 * lane], b = sp[2 * lane + 1];   // 8 consecutive elements
  float ss = a.x*a.x + a.y*a.y + a.z*a.z + a.w*a.w
           + b.x*b.x + b.y*b.y + b.z*b.z + b.w*b.w;
  float am = fmaxf(fmaxf(fmaxf(fabsf(a.x), fabsf(a.y)),
                         fmaxf(fabsf(a.z), fabsf(a.w))),
                   fmaxf(fmaxf(fabsf(b.x), fabsf(b.y)),
                         fmaxf(fabsf(b.z), fabsf(b.w))));
  #pragma unroll
  for (int off = 1; off < 64; off <<= 1) {
    ss += __shfl_xor(ss, off);
    am = fmaxf(am, __shfl_xor(am, off));
  }
  am = fmaxf(am, 1e-30f);
  float iv = 1.0f / fmaxf(sqrtf(ss), 1e-12f);
  float qs = 127.0f / am;
  if (lane == 0) { inv[row] = iv; scale[row] = am * iv * (1.0f / 127.0f); }
  uint2 o;
  o.x = pk4(a.x, a.y, a.z, a.w, qs);
  o.y = pk4(b.x, b.y, b.z, b.w, qs);
  ((uint2*)(dst + (size_t)row * D_DIM))[lane] = o;
}

// ------------------------------------- fused i8 GEMM + exp + row-reduce
// 256x128 tile, BK=64, 4 waves (2Mx2N, 256 threads), mfma_i32_16x16x64_i8.
// 50 KB LDS -> 2 independent blocks resident per CU: block A's VALU epilogue
// overlaps block B's MFMA K-loop (the m114 cross-block mechanism). One
// s_barrier + one own-wave vmcnt(0) per K-tile; setprio around MFMA cluster.
// Epilogue diet: no clamp (max |cos_q| <= 0.3 on this data, proven margin),
// SCALE_LN2 folded into sb2[], pad-col guard replaced by additive -1e38 in
// the fma feeding exp2 (exp2(-1e38) = 0; pad acc = 0 so no NaN).
__global__ __launch_bounds__(256, 2) void gemm_fused(
    const signed char* __restrict__ A, const signed char* __restrict__ B,
    const float* __restrict__ sa_img, const float* __restrict__ sb_w,
    float* __restrict__ partials)
{
  __shared__ __align__(16) signed char Aq[2][256 * 64];
  __shared__ __align__(16) signed char Bq[2][128 * 64];
  __shared__ float red2[2][256];

  const int tid  = threadIdx.x;
  const int lane = tid & 63;
  const int w    = tid >> 6;            // 0..3
  const int l15  = lane & 15;
  const int l4   = lane >> 4;

  // T1 chunked swizzle: NWG = 3128 = 8 * 391 (exact)
  const int p   = blockIdx.x;
  const int g   = (p & 7) * 391 + (p >> 3);
  const int bm  = g & 3;                // 4 M-tiles of 256
  const int bn2 = g >> 2;               // 782 N-tiles of 128
  const int wr  = w >> 1, wc = w & 1;   // 2x2 wave grid

  int4v acc[8][4] = {};
  red2[0][tid] = 0.f; red2[1][tid] = 0.f;

  // staging: per GLD16, lane -> row lane>>2, 16B slot lane&3 (64B rows);
  // source chunk pre-swizzled by (row>>1)&3 = (lane>>3)&3
  const int sgcol = ((lane & 3) ^ ((lane >> 3) & 3)) << 4;
  const int grow  = lane >> 2;
  const size_t a_base = (size_t)(bm * 256) * D_DIM;
  const size_t b_base = (size_t)(bn2 * 128) * D_DIM;
  // read-side swizzle: 16B slot = l4 ^ ((row>>1)&3), row = 16k + l15
  const int sw4 = ((l4 ^ ((l15 >> 1) & 3)) << 4);

  #define STG_A(slot, kt, i) GLD16( \
      A + a_base + (size_t)(w*64 + (i)*16 + grow) * D_DIM + (kt)*64 + sgcol, \
      &Aq[slot][(w*64 + (i)*16) * 64])
  #define STG_B(slot, kt, i) GLD16( \
      B + b_base + (size_t)(w*32 + (i)*16 + grow) * D_DIM + (kt)*64 + sgcol, \
      &Bq[slot][(w*32 + (i)*16) * 64])
  #define STAGE(slot, kt) do { \
    STG_A(slot, kt, 0); STG_A(slot, kt, 1); \
    STG_A(slot, kt, 2); STG_A(slot, kt, 3); \
    STG_B(slot, kt, 0); STG_B(slot, kt, 1); } while (0)

  #define READ_B() do { _Pragma("unroll") \
    for (int n = 0; n < 4; ++n) { \
      int byt = (wc*64 + n*16 + l15) * 64 + sw4; \
      bf[n] = *(const int4v*)(Bb + byt); } } while (0)
  #define READ_A(dst, mh) do { _Pragma("unroll") \
    for (int mi = 0; mi < 4; ++mi) { \
      int byt = (wr*128 + (mh)*64 + mi*16 + l15) * 64 + sw4; \
      dst[mi] = *(const int4v*)(Ab + byt); } } while (0)
  #define MFMA16(mh, af) do { _Pragma("unroll") \
    for (int mi = 0; mi < 4; ++mi) { _Pragma("unroll") \
      for (int n = 0; n < 4; ++n) \
        acc[(mh)*4+mi][n] = __builtin_amdgcn_mfma_i32_16x16x64_i8( \
            af[mi], bf[n], acc[(mh)*4+mi][n], 0, 0, 0); } } while (0)

  #define BAR()   do { asm volatile("" ::: "memory"); \
                       __builtin_amdgcn_s_barrier(); \
                       asm volatile("" ::: "memory"); } while (0)
  #define VM0()   asm volatile("s_waitcnt vmcnt(0)" ::: "memory")

  // prologue: stage tile 0, drain, barrier
  STAGE(0, 0);
  VM0();
  BAR();

  #pragma unroll
  for (int kt = 0; kt < 8; ++kt) {
    const int cur = kt & 1;
    const char* Ab = (const char*)Aq[cur];
    const char* Bb = (const char*)Bq[cur];

    if (kt < 7) STAGE(cur ^ 1, kt + 1);   // issue first (oldest in queue)

    int4v af0[4], af1[4], bf[4];
    READ_B(); READ_A(af0, 0); READ_A(af1, 1);   // 12 x ds_read_b128
    __builtin_amdgcn_s_setprio(1);
    MFMA16(0, af0);
    MFMA16(1, af1);
    __builtin_amdgcn_s_setprio(0);

    if (kt < 7) VM0();   // own 6 stage loads: issued a whole body ago (L2)
    BAR();
  }

  // epilogue: dequant + exp2 + reduce over this block's 128 cols per row.
  // C/D layout (m89, dtype-independent): col = lane&15, row = (lane>>4)*4 + j
  const int rowg0 = bm * 256 + wr * 128;
  float sb2[4], off[4];
  #pragma unroll
  for (int n = 0; n < 4; ++n) {
    int gcol = bn2 * 128 + wc * 64 + n * 16 + l15;
    sb2[n] = sb_w[gcol] * SCALE_LN2;
    off[n] = (gcol < C_CLS) ? 0.f : -1e38f;
  }
  #pragma unroll
  for (int m = 0; m < 8; ++m) {
    #pragma unroll
    for (int j = 0; j < 4; ++j) {
      float sa = sa_img[rowg0 + m * 16 + l4 * 4 + j];
      float s = 0.f;
      #pragma unroll
      for (int n = 0; n < 4; ++n) {
        float x = (float)acc[m][n][j] * sa;
        s += __builtin_amdgcn_exp2f(fmaf(x, sb2[n], off[n]));
      }
      #pragma unroll
      for (int o = 1; o < 16; o <<= 1) s += __shfl_xor(s, o);
      if (l15 == 0)
        red2[wc][wr * 128 + m * 16 + l4 * 4 + j] = s;   // unique writer
    }
  }
  __syncthreads();
  partials[(size_t)bn2 * 1024 + bm * 256 + tid] = red2[0][tid] + red2[1][tid];

  #undef STG_A
  #undef STG_B
  #undef STAGE
  #undef READ_A
  #undef READ_B
  #undef MFMA16
  #undef BAR
  #undef VM0
}

// ---------------------------------------------------------------- zero rows
__global__ void zero_rows(float* p) {
  p[blockIdx.x * 256 + threadIdx.x] = 0.f;
}

// ------------------- row_sums[r] += partials chunk sums (32 blocks, atomic)
__global__ __launch_bounds__(256) void reduce_partials(
    const float* __restrict__ partials, float* __restrict__ row_sums)
{
  const int c = blockIdx.x >> 2;                  // bn-chunk 0..7
  const int gid = (blockIdx.x & 3) * 256 + threadIdx.x;
  const int b0 = c * 98;
  const int b1 = (b0 + 98 < NT_N2) ? b0 + 98 : NT_N2;
  float s = 0.f;
  for (int bn = b0; bn < b1; ++bn)
    s += partials[(size_t)bn * 1024 + gid];
  atomicAdd(&row_sums[gid], s);
}

// ---------------------------------------- per-row margin fixup + row loss
// Subtracts the quantized target term BIT-EXACTLY (same i32 dot + same float
// expression as the GEMM epilogue: x = cvt(id)*sa; exp2(fma(x, sb*S, 0))).
__global__ __launch_bounds__(256) void fix_loss(
    const float* __restrict__ images, const float* __restrict__ weight,
    const int* __restrict__ labels, const float* __restrict__ img_inv,
    const float* __restrict__ w_inv,
    const signed char* __restrict__ ne_q, const signed char* __restrict__ nw_q,
    const float* __restrict__ sa_img, const float* __restrict__ sb_w,
    const float* __restrict__ row_sums, float* __restrict__ loss_buf)
{
  int row = blockIdx.x * 4 + (threadIdx.x >> 6);
  int lane = threadIdx.x & 63;
  int lab = labels[row];
  const float4* ip = (const float4*)(images + (size_t)row * D_DIM);
  const float4* wp = (const float4*)(weight + (size_t)lab * D_DIM);
  float4 a = ip[lane],       b = wp[lane];
  float4 a2 = ip[lane + 64], b2 = wp[lane + 64];
  float dot = a.x*b.x + a.y*b.y + a.z*b.z + a.w*b.w
            + a2.x*b2.x + a2.y*b2.y + a2.z*b2.z + a2.w*b2.w;
  uint2 ua = ((const uint2*)(ne_q + (size_t)row * D_DIM))[lane];
  uint2 ub = ((const uint2*)(nw_q + (size_t)lab * D_DIM))[lane];
  int id = dp8(ua.x, ub.x) + dp8(ua.y, ub.y);
  #pragma unroll
  for (int off = 1; off < 64; off <<= 1) {
    dot += __shfl_xor(dot, off);
    id  += __shfl_xor(id, off);
  }
  if (lane == 0) {
    // quantized target logit — identical expression to GEMM epilogue
    float x = (float)id * sa_img[row];
    float eq = __builtin_amdgcn_exp2f(fmaf(x, sb_w[lab] * SCALE_LN2, 0.f));
    // f32-exact target cosine + ArcFace margin
    float t = dot * img_inv[row] * w_inv[lab];
    t = fminf(fmaxf(t, -1.f), 1.f);
    float tadj = t * COS_M - sqrtf(fmaxf(1.f - t * t, 0.f)) * SIN_M;
    float s = row_sums[row] - eq
            + __builtin_amdgcn_exp2f(tadj * SCALE_LN2);
    loss_buf[row] = logf(s) - 64.f * tadj;
  }
}

// ------------------------------------------------------------ final mean
__global__ void final_reduce(const float* __restrict__ loss_buf,
                             float* __restrict__ out)
{
  __shared__ float sh[16];
  int tid = threadIdx.x;
  float v = loss_buf[tid];
  #pragma unroll
  for (int off = 1; off < 64; off <<= 1) v += __shfl_xor(v, off);
  if ((tid & 63) == 0) sh[tid >> 6] = v;
  __syncthreads();
  if (tid < 16) {
    float w = sh[tid];
    #pragma unroll
    for (int off = 1; off < 16; off <<= 1) w += __shfl_xor(w, off);
    if (tid == 0) out[0] = w * (1.0f / 1024.0f);
  }
}

// ----------------------------------------------------------------- launch
extern "C" void kernel_launch(void* const* d_in, const int* in_sizes, int n_in,
                              void* d_out, int out_size, void* d_ws, size_t ws_size,
                              hipStream_t stream) {
  const float* images = (const float*)d_in[0];
  const int*   labels = (const int*)d_in[1];
  const float* weight = (const float*)d_in[2];
  float* out = (float*)d_out;
  char* ws = (char*)d_ws;

  // workspace layout (512B-aligned offsets)
  float*       row_sums = (float*)(ws + 0);          //  4 KB
  float*       loss_buf = (float*)(ws + 4096);       //  4 KB
  float*       img_inv  = (float*)(ws + 8192);       //  4 KB
  float*       w_inv    = (float*)(ws + 12288);      //  ~400 KB
  float*       sa_img   = (float*)(ws + 413696);     //  4 KB
  float*       sb_w     = (float*)(ws + 417792);     //  ~400 KB (C_PAD)
  float*       partials = (float*)(ws + 819200);     //  ~3.2 MB [782][1024]
  signed char* ne_q     = (signed char*)(ws + 4096000);  // 512 KB [1024][512]
  signed char* nw_q     = (signed char*)(ws + 4620288);  // ~51 MB [C_PAD][512]

  norm_q<<<N_IMG / 4, 256, 0, stream>>>(images, ne_q, sa_img, img_inv,
                                        N_IMG, N_IMG);
  norm_q<<<C_PAD / 4, 256, 0, stream>>>(weight, nw_q, sb_w, w_inv,
                                        C_CLS, C_PAD);
  zero_rows<<<4, 256, 0, stream>>>(row_sums);
  gemm_fused<<<NWG, 256, 0, stream>>>(ne_q, nw_q, sa_img, sb_w, partials);
  reduce_partials<<<32, 256, 0, stream>>>(partials, row_sums);
  fix_loss<<<N_IMG / 4, 256, 0, stream>>>(images, weight, labels, img_inv,
                                          w_inv, ne_q, nw_q, sa_img, sb_w,
                                          row_sums, loss_buf);
  final_reduce<<<1, 1024, 0, stream>>>(loss_buf, out);
}

// Round 9
// 157.842 us; speedup vs baseline: 1.1452x; 1.1452x over previous
//
#include <hip/hip_runtime.h>
#include <cstdint>

#define N_IMG 1024
#define D_DIM 512
#define C_CLS 100000
#define C_PAD 100096            // 391 * 256
#define NT_N 391
#define NWG (4 * NT_N)          // 1564 blocks
#define SCALE_LN2 92.33248261689366f  // 64 / ln(2)
#define COS_M 0.8775825618903728f
#define SIN_M 0.479425538604203f

typedef __attribute__((ext_vector_type(4))) int int4v;

#define GLD16(g, l) __builtin_amdgcn_global_load_lds( \
    (const __attribute__((address_space(1))) void*)(g), \
    (__attribute__((address_space(3))) void*)(l), 16, 0, 0)

static __device__ __forceinline__ uint pk4(float a, float b, float c, float d,
                                           float qs) {
  int ia = (int)rintf(a * qs), ib = (int)rintf(b * qs);
  int ic = (int)rintf(c * qs), id = (int)rintf(d * qs);
  return (ia & 255) | ((ib & 255) << 8) | ((ic & 255) << 16) | ((id & 255) << 24);
}

static __device__ __forceinline__ int dp8(uint a, uint b) {
  int s = 0;
  #pragma unroll
  for (int i = 0; i < 4; ++i)
    s += (int)(signed char)((a >> (8 * i)) & 255) *
         (int)(signed char)((b >> (8 * i)) & 255);
  return s;
}

// DPP reduction step over 16-lane rows (VALU pipe — no LDS ops)
template <int CTRL>
static __device__ __forceinline__ float dpp_red(float s) {
  int t = __builtin_amdgcn_update_dpp(0, __builtin_bit_cast(int, s),
                                      CTRL, 0xF, 0xF, false);
  return s + __builtin_bit_cast(float, t);
}

// --------------------------- row L2-normalize + symmetric int8 quantization
__global__ __launch_bounds__(256) void norm_q(
    const float* __restrict__ src, signed char* __restrict__ dst,
    float* __restrict__ scale, float* __restrict__ inv, int nvalid, int nrows)
{
  int row = blockIdx.x * 4 + (threadIdx.x >> 6);
  int lane = threadIdx.x & 63;
  if (row >= nrows) return;
  if (row >= nvalid) {                 // pad rows: zero q + zero scale
    uint2 z; z.x = 0u; z.y = 0u;
    ((uint2*)(dst + (size_t)row * D_DIM))[lane] = z;
    if (lane == 0) scale[row] = 0.f;
    return;
  }
  const float4* sp = (const float4*)(src + (size_t)row * D_DIM);
  float4 a = sp[2 * lane], b = sp[2 * lane + 1];   // 8 consecutive elements
  float ss = a.x*a.x + a.y*a.y + a.z*a.z + a.w*a.w
           + b.x*b.x + b.y*b.y + b.z*b.z + b.w*b.w;
  float am = fmaxf(fmaxf(fmaxf(fabsf(a.x), fabsf(a.y)),
                         fmaxf(fabsf(a.z), fabsf(a.w))),
                   fmaxf(fmaxf(fabsf(b.x), fabsf(b.y)),
                         fmaxf(fabsf(b.z), fabsf(b.w))));
  #pragma unroll
  for (int off = 1; off < 64; off <<= 1) {
    ss += __shfl_xor(ss, off);
    am = fmaxf(am, __shfl_xor(am, off));
  }
  am = fmaxf(am, 1e-30f);
  float iv = 1.0f / fmaxf(sqrtf(ss), 1e-12f);
  float qs = 127.0f / am;
  if (lane == 0) { inv[row] = iv; scale[row] = am * iv * (1.0f / 127.0f); }
  uint2 o;
  o.x = pk4(a.x, a.y, a.z, a.w, qs);
  o.y = pk4(b.x, b.y, b.z, b.w, qs);
  ((uint2*)(dst + (size_t)row * D_DIM))[lane] = o;
}

// ------------------------------------- fused i8 GEMM + exp + row-reduce
// m201 8-phase port, i8 adaptation: 256x256 tile, BK=64, 8 waves (2Mx4N),
// mfma_i32_16x16x64_i8. 4 phases per K-tile, each:
//   {<=6 ds_read | 1 global_load_lds (tile kt+2) | s_barrier | lgkmcnt(0)
//    | setprio(1) 8xMFMA setprio(0) | [phase3: vmcnt(4)] | s_barrier}
// 3-slot LDS, loads issued 2 K-tiles ahead, own-wave counted vmcnt(4) once
// per K-tile (never 0 in steady state) before the barrier that publishes it.
// NO sched_barrier pins (r3 lesson). T1 bijective XCD swizzle. LDS XOR
// swizzle ((row>>1)&3 on 16B granules) — verified 0 conflicts (r7/r8).
__global__ __launch_bounds__(512, 2) void gemm_fused(
    const signed char* __restrict__ A, const signed char* __restrict__ B,
    const float* __restrict__ sa_img, const float* __restrict__ sb_w,
    float* __restrict__ partials)
{
  __shared__ __align__(16) signed char Aq[3][256 * 64];
  __shared__ __align__(16) signed char Bq[3][256 * 64];
  __shared__ float red4[4][256];

  const int tid  = threadIdx.x;
  const int lane = tid & 63;
  const int w    = tid >> 6;            // 0..7
  const int l15  = lane & 15;
  const int l4   = lane >> 4;

  // T1 bijective swizzle: NWG=1564, q=195, r=4
  const int p   = blockIdx.x;
  const int xcd = p & 7, idx = p >> 3;
  const int g   = (xcd < 4 ? xcd * 196 : 784 + (xcd - 4) * 195) + idx;
  const int bm  = g & 3;
  const int bn  = g >> 2;
  const int wr  = w >> 2, wc = w & 3;   // 2x4 wave grid

  int4v acc[8][4] = {};

  // staging: chunk c = 16 rows (1 KB); lane -> row c*16 + (lane>>2),
  // 16B slot lane&3; source pre-swizzled by (row>>1)&3 = (lane>>3)&3
  const int sgcol = ((lane & 3) ^ ((lane >> 3) & 3)) << 4;
  const int grow  = lane >> 2;
  const size_t a_base = (size_t)(bm * 256) * D_DIM;
  const size_t b_base = (size_t)(bn * 256) * D_DIM;
  // read-side swizzle: 16B slot = l4 ^ ((row>>1)&3), row = 16k + l15
  const int sw4 = ((l4 ^ ((l15 >> 1) & 3)) << 4);

  #define STG_A(slot, kt, c) GLD16( \
      A + a_base + (size_t)((c)*16 + grow) * D_DIM + (kt)*64 + sgcol, \
      &Aq[slot][(c) * 1024])
  #define STG_B(slot, kt, c) GLD16( \
      B + b_base + (size_t)((c)*16 + grow) * D_DIM + (kt)*64 + sgcol, \
      &Bq[slot][(c) * 1024])

  #define READ_B() do { _Pragma("unroll") \
    for (int n = 0; n < 4; ++n) { \
      int byt = (wc*64 + n*16 + l15) * 64 + sw4; \
      bf[n] = *(const int4v*)(Bb + byt); } } while (0)
  #define READ_A2(mg) do { _Pragma("unroll") \
    for (int q = 0; q < 2; ++q) { \
      int byt = (wr*128 + (mg)*32 + q*16 + l15) * 64 + sw4; \
      af[q] = *(const int4v*)(Ab + byt); } } while (0)
  #define MFMA8(mg) do { _Pragma("unroll") \
    for (int q = 0; q < 2; ++q) { _Pragma("unroll") \
      for (int n = 0; n < 4; ++n) \
        acc[(mg)*2+q][n] = __builtin_amdgcn_mfma_i32_16x16x64_i8( \
            af[q], bf[n], acc[(mg)*2+q][n], 0, 0, 0); } } while (0)

  #define BAR()   __builtin_amdgcn_s_barrier()
  #define LGKM0() asm volatile("s_waitcnt lgkmcnt(0)" ::: "memory")
  #define VM(n)   asm volatile("s_waitcnt vmcnt(" #n ")" ::: "memory")
  #define PRIO1() __builtin_amdgcn_s_setprio(1)
  #define PRIO0() __builtin_amdgcn_s_setprio(0)

  // prologue: stage tiles 0 and 1 (8 loads/wave), wait tile 0 only
  STG_A(0, 0, 2*w); STG_A(0, 0, 2*w+1); STG_B(0, 0, 2*w); STG_B(0, 0, 2*w+1);
  STG_A(1, 1, 2*w); STG_A(1, 1, 2*w+1); STG_B(1, 1, 2*w); STG_B(1, 1, 2*w+1);
  VM(4);
  BAR();

  #pragma unroll
  for (int kt = 0; kt < 8; ++kt) {
    const int sR = kt % 3;            // compile-time (loop unrolled)
    const int sS = (kt + 2) % 3;
    const char* Ab = (const char*)Aq[sR];
    const char* Bb = (const char*)Bq[sR];
    const bool st = (kt < 6);
    int4v af[2], bf[4];

    // ---- phase 0: mg=0 (reads all B + A m=0,1)
    READ_B(); READ_A2(0);
    if (st) STG_A(sS, kt + 2, 2*w);
    BAR(); LGKM0();
    PRIO1(); MFMA8(0); PRIO0();
    BAR();

    // ---- phase 1: mg=1
    READ_A2(1);
    if (st) STG_A(sS, kt + 2, 2*w + 1);
    BAR(); LGKM0();
    PRIO1(); MFMA8(1); PRIO0();
    BAR();

    // ---- phase 2: mg=2
    READ_A2(2);
    if (st) STG_B(sS, kt + 2, 2*w);
    BAR(); LGKM0();
    PRIO1(); MFMA8(2); PRIO0();
    BAR();

    // ---- phase 3: mg=3, then the single counted gate for tile kt+1
    READ_A2(3);
    if (st) STG_B(sS, kt + 2, 2*w + 1);
    BAR(); LGKM0();
    PRIO1(); MFMA8(3); PRIO0();
    if (kt < 6)       { VM(4); }   // tile kt+1 done; kt+2's 4 stay in flight
    else if (kt == 6) { VM(0); }   // drain tile 7
    BAR();
  }

  // epilogue: dequant + exp2 + DPP row-reduce (no LDS-pipe shuffles).
  // C/D layout (m89, dtype-independent): col = lane&15, row = (lane>>4)*4 + j
  const int rowg0 = bm * 256 + wr * 128;
  float sb2[4], off[4];
  #pragma unroll
  for (int n = 0; n < 4; ++n) {
    int gcol = bn * 256 + wc * 64 + n * 16 + l15;
    sb2[n] = sb_w[gcol] * SCALE_LN2;
    off[n] = (gcol < C_CLS) ? 0.f : -1e38f;
  }
  #pragma unroll
  for (int m = 0; m < 8; ++m) {
    #pragma unroll
    for (int j = 0; j < 4; ++j) {
      float sa = sa_img[rowg0 + m * 16 + l4 * 4 + j];
      float s = 0.f;
      #pragma unroll
      for (int n = 0; n < 4; ++n) {
        float x = (float)acc[m][n][j] * sa;
        s += __builtin_amdgcn_exp2f(fmaf(x, sb2[n], off[n]));
      }
      // sum over the 16 l15 lanes: quad_perm xor1, xor2, then row_ror 4, 8
      s = dpp_red<0xB1>(s);
      s = dpp_red<0x4E>(s);
      s = dpp_red<0x124>(s);
      s = dpp_red<0x128>(s);
      if (l15 == 0)
        red4[wc][wr * 128 + m * 16 + l4 * 4 + j] = s;   // unique writer
    }
  }
  __syncthreads();
  if (tid < 256)
    partials[(size_t)bn * 1024 + bm * 256 + tid] =
        red4[0][tid] + red4[1][tid] + red4[2][tid] + red4[3][tid];

  #undef STG_A
  #undef STG_B
  #undef READ_B
  #undef READ_A2
  #undef MFMA8
  #undef BAR
  #undef LGKM0
  #undef VM
  #undef PRIO1
  #undef PRIO0
}

// ---------------------------------------------------------------- zero rows
__global__ void zero_rows(float* p) {
  p[blockIdx.x * 256 + threadIdx.x] = 0.f;
}

// ------------------- row_sums[r] += partials chunk sums (32 blocks, atomic)
__global__ __launch_bounds__(256) void reduce_partials(
    const float* __restrict__ partials, float* __restrict__ row_sums)
{
  const int c = blockIdx.x >> 2;                  // bn-chunk 0..7
  const int gid = (blockIdx.x & 3) * 256 + threadIdx.x;
  const int b0 = c * 49;
  const int b1 = (b0 + 49 < NT_N) ? b0 + 49 : NT_N;
  float s = 0.f;
  for (int bn = b0; bn < b1; ++bn)
    s += partials[(size_t)bn * 1024 + gid];
  atomicAdd(&row_sums[gid], s);
}

// ---------------------------------------- per-row margin fixup + row loss
// Subtracts the quantized target term BIT-EXACTLY (same i32 dot + same float
// expression as the GEMM epilogue: x = cvt(id)*sa; exp2(fma(x, sb*S, 0))).
__global__ __launch_bounds__(256) void fix_loss(
    const float* __restrict__ images, const float* __restrict__ weight,
    const int* __restrict__ labels, const float* __restrict__ img_inv,
    const float* __restrict__ w_inv,
    const signed char* __restrict__ ne_q, const signed char* __restrict__ nw_q,
    const float* __restrict__ sa_img, const float* __restrict__ sb_w,
    const float* __restrict__ row_sums, float* __restrict__ loss_buf)
{
  int row = blockIdx.x * 4 + (threadIdx.x >> 6);
  int lane = threadIdx.x & 63;
  int lab = labels[row];
  const float4* ip = (const float4*)(images + (size_t)row * D_DIM);
  const float4* wp = (const float4*)(weight + (size_t)lab * D_DIM);
  float4 a = ip[lane],       b = wp[lane];
  float4 a2 = ip[lane + 64], b2 = wp[lane + 64];
  float dot = a.x*b.x + a.y*b.y + a.z*b.z + a.w*b.w
            + a2.x*b2.x + a2.y*b2.y + a2.z*b2.z + a2.w*b2.w;
  uint2 ua = ((const uint2*)(ne_q + (size_t)row * D_DIM))[lane];
  uint2 ub = ((const uint2*)(nw_q + (size_t)lab * D_DIM))[lane];
  int id = dp8(ua.x, ub.x) + dp8(ua.y, ub.y);
  #pragma unroll
  for (int off = 1; off < 64; off <<= 1) {
    dot += __shfl_xor(dot, off);
    id  += __shfl_xor(id, off);
  }
  if (lane == 0) {
    // quantized target logit — identical expression to GEMM epilogue
    float x = (float)id * sa_img[row];
    float eq = __builtin_amdgcn_exp2f(fmaf(x, sb_w[lab] * SCALE_LN2, 0.f));
    // f32-exact target cosine + ArcFace margin
    float t = dot * img_inv[row] * w_inv[lab];
    t = fminf(fmaxf(t, -1.f), 1.f);
    float tadj = t * COS_M - sqrtf(fmaxf(1.f - t * t, 0.f)) * SIN_M;
    float s = row_sums[row] - eq
            + __builtin_amdgcn_exp2f(tadj * SCALE_LN2);
    loss_buf[row] = logf(s) - 64.f * tadj;
  }
}

// ------------------------------------------------------------ final mean
__global__ void final_reduce(const float* __restrict__ loss_buf,
                             float* __restrict__ out)
{
  __shared__ float sh[16];
  int tid = threadIdx.x;
  float v = loss_buf[tid];
  #pragma unroll
  for (int off = 1; off < 64; off <<= 1) v += __shfl_xor(v, off);
  if ((tid & 63) == 0) sh[tid >> 6] = v;
  __syncthreads();
  if (tid < 16) {
    float w = sh[tid];
    #pragma unroll
    for (int off = 1; off < 16; off <<= 1) w += __shfl_xor(w, off);
    if (tid == 0) out[0] = w * (1.0f / 1024.0f);
  }
}

// ----------------------------------------------------------------- launch
extern "C" void kernel_launch(void* const* d_in, const int* in_sizes, int n_in,
                              void* d_out, int out_size, void* d_ws, size_t ws_size,
                              hipStream_t stream) {
  const float* images = (const float*)d_in[0];
  const int*   labels = (const int*)d_in[1];
  const float* weight = (const float*)d_in[2];
  float* out = (float*)d_out;
  char* ws = (char*)d_ws;

  // workspace layout (512B-aligned offsets)
  float*       row_sums = (float*)(ws + 0);          //  4 KB
  float*       loss_buf = (float*)(ws + 4096);       //  4 KB
  float*       img_inv  = (float*)(ws + 8192);       //  4 KB
  float*       w_inv    = (float*)(ws + 12288);      //  ~400 KB
  float*       sa_img   = (float*)(ws + 413696);     //  4 KB
  float*       sb_w     = (float*)(ws + 417792);     //  ~400 KB (C_PAD)
  float*       partials = (float*)(ws + 819200);     //  ~1.6 MB [391][1024]
  signed char* ne_q     = (signed char*)(ws + 2420736);  // 512 KB [1024][512]
  signed char* nw_q     = (signed char*)(ws + 2945024);  // ~51 MB [C_PAD][512]

  norm_q<<<N_IMG / 4, 256, 0, stream>>>(images, ne_q, sa_img, img_inv,
                                        N_IMG, N_IMG);
  norm_q<<<C_PAD / 4, 256, 0, stream>>>(weight, nw_q, sb_w, w_inv,
                                        C_CLS, C_PAD);
  zero_rows<<<4, 256, 0, stream>>>(row_sums);
  gemm_fused<<<NWG, 512, 0, stream>>>(ne_q, nw_q, sa_img, sb_w, partials);
  reduce_partials<<<32, 256, 0, stream>>>(partials, row_sums);
  fix_loss<<<N_IMG / 4, 256, 0, stream>>>(images, weight, labels, img_inv,
                                          w_inv, ne_q, nw_q, sa_img, sb_w,
                                          row_sums, loss_buf);
  final_reduce<<<1, 1024, 0, stream>>>(loss_buf, out);
}